// Round 1
// baseline (24.323 us; speedup 1.0000x reference)
//
#include <hip/hip_runtime.h>

#define BATCH 1024
#define FEAT_DIM 512
// 128 threads * 4 floats (float4) = 512 = FEAT_DIM, one block per sample.

__global__ __launch_bounds__(128) void center_loss_kernel(
    const float* __restrict__ x,
    const int* __restrict__ labels,
    const float* __restrict__ centers,
    float* __restrict__ out)
{
    const int b   = blockIdx.x;   // sample index
    const int tid = threadIdx.x;  // 0..127

    const int label = labels[b];

    const float4* __restrict__ xr =
        reinterpret_cast<const float4*>(x + (size_t)b * FEAT_DIM);
    const float4* __restrict__ cr =
        reinterpret_cast<const float4*>(centers + (size_t)label * FEAT_DIM);

    const float4 xv = xr[tid];
    const float4 cv = cr[tid];

    const float dx = xv.x - cv.x;
    const float dy = xv.y - cv.y;
    const float dz = xv.z - cv.z;
    const float dw = xv.w - cv.w;
    float s = dx * dx + dy * dy + dz * dz + dw * dw;

    // Wave-level reduction across 64 lanes.
    #pragma unroll
    for (int off = 32; off > 0; off >>= 1)
        s += __shfl_down(s, off, 64);

    // Combine the block's 2 waves via LDS.
    __shared__ float wsum[2];
    const int wave = tid >> 6;
    const int lane = tid & 63;
    if (lane == 0) wsum[wave] = s;
    __syncthreads();

    if (tid == 0) {
        const float total = wsum[0] + wsum[1];
        atomicAdd(out, total * (0.5f / (float)BATCH));
    }
}

extern "C" void kernel_launch(void* const* d_in, const int* in_sizes, int n_in,
                              void* d_out, int out_size, void* d_ws, size_t ws_size,
                              hipStream_t stream) {
    const float* x       = (const float*)d_in[0];
    const int*   labels  = (const int*)d_in[1];
    const float* centers = (const float*)d_in[2];
    float*       out     = (float*)d_out;

    // d_out is poisoned (0xAA) before timing and never re-poisoned between
    // replays — zero it ourselves every call (async memset is graph-capturable).
    hipMemsetAsync(out, 0, sizeof(float), stream);

    center_loss_kernel<<<BATCH, 128, 0, stream>>>(x, labels, centers, out);
}

// Round 2
// 11.252 us; speedup vs baseline: 2.1616x; 2.1616x over previous
//
#include <hip/hip_runtime.h>

#define BATCH 1024
#define FEAT_DIM 512

// Kernel 1: one 64-lane wave per sample. 256 blocks x 256 threads (4 waves).
// Each lane loads 8 contiguous floats (two float4) of x and of the gathered
// center row, accumulates squared diff, wave shuffle-reduce, lane 0 writes
// the per-sample partial to ws[b]. No LDS, no barriers, no atomics.
__global__ __launch_bounds__(256) void cl_partial(
    const float* __restrict__ x,
    const int* __restrict__ labels,
    const float* __restrict__ centers,
    float* __restrict__ ws)
{
    const int wave = threadIdx.x >> 6;
    const int lane = threadIdx.x & 63;
    const int b    = blockIdx.x * 4 + wave;

    const int label = labels[b];

    const float4* __restrict__ xr =
        reinterpret_cast<const float4*>(x + (size_t)b * FEAT_DIM);
    const float4* __restrict__ cr =
        reinterpret_cast<const float4*>(centers + (size_t)label * FEAT_DIM);

    const float4 a0 = xr[lane];
    const float4 a1 = xr[lane + 64];
    const float4 c0 = cr[lane];
    const float4 c1 = cr[lane + 64];

    float d0 = a0.x - c0.x, d1 = a0.y - c0.y, d2 = a0.z - c0.z, d3 = a0.w - c0.w;
    float d4 = a1.x - c1.x, d5 = a1.y - c1.y, d6 = a1.z - c1.z, d7 = a1.w - c1.w;

    float s = d0 * d0 + d1 * d1 + d2 * d2 + d3 * d3
            + d4 * d4 + d5 * d5 + d6 * d6 + d7 * d7;

    #pragma unroll
    for (int off = 32; off > 0; off >>= 1)
        s += __shfl_down(s, off, 64);

    if (lane == 0) ws[b] = s;
}

// Kernel 2: single wave reduces the 1024 partials (256 float4s, 4 per lane).
__global__ __launch_bounds__(64) void cl_final(
    const float* __restrict__ ws,
    float* __restrict__ out)
{
    const int lane = threadIdx.x;
    const float4* __restrict__ w = reinterpret_cast<const float4*>(ws);

    const float4 v0 = w[lane];
    const float4 v1 = w[lane + 64];
    const float4 v2 = w[lane + 128];
    const float4 v3 = w[lane + 192];

    float s = v0.x + v0.y + v0.z + v0.w
            + v1.x + v1.y + v1.z + v1.w
            + v2.x + v2.y + v2.z + v2.w
            + v3.x + v3.y + v3.z + v3.w;

    #pragma unroll
    for (int off = 32; off > 0; off >>= 1)
        s += __shfl_down(s, off, 64);

    if (lane == 0) out[0] = s * (0.5f / (float)BATCH);
}

extern "C" void kernel_launch(void* const* d_in, const int* in_sizes, int n_in,
                              void* d_out, int out_size, void* d_ws, size_t ws_size,
                              hipStream_t stream) {
    const float* x       = (const float*)d_in[0];
    const int*   labels  = (const int*)d_in[1];
    const float* centers = (const float*)d_in[2];
    float*       out     = (float*)d_out;
    float*       ws      = (float*)d_ws;

    cl_partial<<<BATCH / 4, 256, 0, stream>>>(x, labels, centers, ws);
    cl_final<<<1, 64, 0, stream>>>(ws, out);
}